// Round 6
// baseline (586.000 us; speedup 1.0000x reference)
//
#include <hip/hip_runtime.h>
#include <hip/hip_bf16.h>
#include <cstdint>

#define N_ATOMS 100000
#define NFEAT   256
#define NMOL    1024
#define NU      6256    // 100096 / 16 atoms per unit
#define NPAD    100096  // NU*16: Ab and H1 padded to this many rows

static constexpr float SCALE_C = 5.992277830325989f;
static constexpr float SHIFT_C = -406274.63784969115f;

typedef __attribute__((ext_vector_type(8))) short short8;    // bf16x8 MFMA operand
typedef __attribute__((ext_vector_type(4))) float float4_t;  // f32x4 accumulator

__device__ __forceinline__ unsigned short f2bf(float x) {
    union { float f; uint32_t u; } v; v.f = x;
    uint32_t r = (v.u + 0x7fffu + ((v.u >> 16) & 1u)) >> 16;
    return (unsigned short)r;
}

// pack two fp32 -> two bf16 (+0x8000 truncate-high, bit-identical to the
// conversion used in every passing round) in one v_perm
__device__ __forceinline__ uint32_t pk(float lo, float hi) {
    union { float f; uint32_t u; } a, b; a.f = lo; b.f = hi;
    return __builtin_amdgcn_perm(b.u + 0x8000u, a.u + 0x8000u, 0x07060302u);
}

__device__ __forceinline__ float silu(float x) {
    return x / (1.0f + __expf(-x));
}

// async global->LDS, 16B/lane; LDS dest wave-uniform, lane i lands at +i*16B
__device__ __forceinline__ void async16(void* lds, const void* g) {
    __builtin_amdgcn_global_load_lds(
        (const __attribute__((address_space(1))) unsigned int*)(uintptr_t)g,
        (__attribute__((address_space(3))) unsigned int*)(uint32_t)(uintptr_t)lds,
        16, 0, 0);
}

// Global W image (written by prep, R4-verified layout):
//   pos = (k>>7)*32768 + n*128 + (((k>>3 & 15) ^ (n&15))&15)<<3 + (k&7)
// Col-half ch of plane p = contiguous 32 KB at p*32768 + ch*16384.
// LDS one 64 KB col-half: lpos = (kc>>4)*16384 + nl*128 + swz (nl&15 == n&15).
__device__ __forceinline__ short8 wfrag_h(const unsigned short* Wlds, int nl, int kc) {
    return *(const short8*)&Wlds[((kc >> 4) << 14) + nl * 128 +
                                 ((((kc & 15) ^ (nl & 15)) & 15) << 3)];
}

// ---------------------------------------------------------------------------
// Prep: b<512: W1,W2 fp32 -> bf16 swizzled images + out[]=SHIFT.
// 512<=b<6762: A fp32 -> Ab bf16 (pk rounding). 6762<=b<6768: zero-fill
// Ab pad rows 100000..100095 so gemm1 is fully branchless (R13).
// ---------------------------------------------------------------------------
__global__ void prep(const float* __restrict__ W1, const float* __restrict__ W2,
                     const float* __restrict__ A,
                     unsigned short* __restrict__ W1i, unsigned short* __restrict__ W2i,
                     unsigned short* __restrict__ Ab, float* __restrict__ out) {
    const int b = blockIdx.x, tid = threadIdx.x;
    if (b < 512) {
        int g = b * 256 + tid;                       // 0 .. 131071
        const float* W = (g < 65536) ? W1 : W2;
        unsigned short* Wi = (g < 65536) ? W1i : W2i;
        int idx = g & 65535;
        int k = idx >> 8, n = idx & 255;
        int kc = (k >> 3) & 15;
        int pos = ((k >> 7) << 15) + n * 128 + (((kc ^ (n & 15)) & 15) << 3) + (k & 7);
        Wi[pos] = f2bf(W[idx]);
        if (g < NMOL) out[g] = SHIFT_C;
    } else if (b < 6762) {
        // 6250 blocks x 256 thr x 16 floats = 25,600,000 = N_ATOMS*256 exactly
        int t = (b - 512) * 256 + tid;
        const float4* af = (const float4*)(A + (size_t)t * 16);
        float4 x0 = af[0], x1 = af[1], x2 = af[2], x3 = af[3];
        uint4 o0 = make_uint4(pk(x0.x, x0.y), pk(x0.z, x0.w),
                              pk(x1.x, x1.y), pk(x1.z, x1.w));
        uint4 o1 = make_uint4(pk(x2.x, x2.y), pk(x2.z, x2.w),
                              pk(x3.x, x3.y), pk(x3.z, x3.w));
        ((uint4*)Ab)[(size_t)t * 2]     = o0;
        ((uint4*)Ab)[(size_t)t * 2 + 1] = o1;
    } else {
        // zero pad rows: 6 blocks x 256 thr x 16 shorts = 24576 = 96*256
        int idx = (b - 6762) * 256 + tid;
        uint4 z = make_uint4(0, 0, 0, 0);
        ((uint4*)(Ab + (size_t)N_ATOMS * 256))[idx * 2]     = z;
        ((uint4*)(Ab + (size_t)N_ATOMS * 256))[idx * 2 + 1] = z;
    }
}

// ---------------------------------------------------------------------------
// Layer 1: H1 = silu(Ab @ W1 + b1), Ab pre-converted bf16 padded to NPAD
// rows. Col-split (R10): 512 blocks x 512 thr, block (bslot,ch) owns cols
// ch*128..+127, 64 KB LDS W -> 2 blocks/CU, 16 waves/CU.
// R13 lesson: at 16 waves/CU the unified budget is 128/wave and with MFMA
// the arch side is ~64 -> any "whole unit upfront" batch (32+ regs) spills
// (R4: f32, R5: bf16 -- both ~500 MB scratch traffic). Fix: depth-3
// ROTATING window (12 regs): consume chunk s while s+1,s+2 are in flight;
// steps 5..7 issue the NEXT unit's chunks 0..2 (steal-ahead at loop top)
// so the pipeline never drains, even across unit boundaries. Branchless:
// pad rows make every load/store valid.
// ---------------------------------------------------------------------------
__global__ __launch_bounds__(512, 4)
void gemm1(const unsigned short* __restrict__ Ab, const unsigned short* __restrict__ Wimg,
           const float* __restrict__ b1, unsigned short* __restrict__ H1) {
    __shared__ unsigned short Wlds[32768];   // 64 KB: one col-half, both k-planes
    __shared__ float b1L[128];
    __shared__ int uctr;

    const int tid = threadIdx.x;
    const int w = tid >> 6, lane = tid & 63;
    const int fl = lane & 15, qd = lane >> 4;
    const int ch = blockIdx.x >> 8;          // col-half 0/1
    const int bslot = blockIdx.x & 255;

    // stage 64 KB half: chunk c (512 shorts) -> plane p=c>>5, in-plane (c&31)*512
#pragma unroll
    for (int i = 0; i < 8; ++i) {
        int c = w * 8 + i;
        async16(&Wlds[c * 512],
                Wimg + ((c >> 5) << 15) + (ch << 14) + ((c & 31) << 9) + lane * 8);
    }
    if (tid < 32) ((float4*)b1L)[tid] = ((const float4*)(b1 + ch * 128))[tid];
    if (tid == 0) uctr = 0;
    __syncthreads();

    // prologue: first unit (t <= 7 -> u < 2048 < NU always) + first 3 chunks
    int u;
    { int tt = 0; if (lane == 0) tt = atomicAdd(&uctr, 1);
      u = bslot + (__shfl(tt, 0) << 8); }
    const unsigned short* ap = Ab + (size_t)(u * 16 + fl) * 256 + qd * 8;
    short8 rr0 = *(const short8*)(ap);
    short8 rr1 = *(const short8*)(ap + 32);
    short8 rr2 = *(const short8*)(ap + 64);

    for (;;) {
        int un;
        { int tt = 0; if (lane == 0) tt = atomicAdd(&uctr, 1);
          un = bslot + (__shfl(tt, 0) << 8); }
        const bool more = (un < NU);
        const unsigned short* apn =
            more ? (Ab + (size_t)(un * 16 + fl) * 256 + qd * 8) : ap;

        short8 rr[3] = {rr0, rr1, rr2};
        float4_t acc[8] = {};
#pragma unroll
        for (int s = 0; s < 8; ++s) {
            short8 av = rr[s % 3];
            // refill the freed slot: chunk s+3 (s>=5 -> next unit's chunk s-5)
            if (s < 5) rr[s % 3] = *(const short8*)(ap + (s + 3) * 32);
            else       rr[s % 3] = *(const short8*)(apn + (s - 5) * 32);
            const int kc = s * 4 + qd;
#pragma unroll
            for (int j = 0; j < 8; ++j) {
                short8 wf = wfrag_h(Wlds, j * 16 + fl, kc);
                acc[j] = __builtin_amdgcn_mfma_f32_16x16x32_bf16(wf, av, acc[j], 0, 0, 0);
            }
        }

        // store current unit (branchless: pad rows are real memory)
        const int row = u * 16 + fl;
#pragma unroll
        for (int j = 0; j < 8; ++j) {
            int nl = j * 16 + qd * 4;          // local col
            float4 b4 = *(const float4*)&b1L[nl];
            uint2 o;
            o.x = pk(silu(acc[j][0] + b4.x), silu(acc[j][1] + b4.y));
            o.y = pk(silu(acc[j][2] + b4.z), silu(acc[j][3] + b4.w));
            *(uint2*)&H1[(size_t)row * 256 + ch * 128 + nl] = o;
        }

        if (!more) break;
        // rotate: after 8 steps the window holds next unit's c0,c1,c2 in
        // slots (2,0,1)
        rr0 = rr[2]; rr1 = rr[0]; rr2 = rr[1];
        u = un; ap = apn;
    }
}

// ---------------------------------------------------------------------------
// Layer 2+3+pool: out[mol] += SCALE*(silu(H1@W2+b2).W3 + b3). Col-split
// partial W3-dot (additive across halves); b3 added only by half 0.
// Same R13 depth-3 rotating window + steal-ahead + branchless loads (H1
// padded rows are valid memory; bucket guard excludes pad atoms).
// b2/W3 halves staged in LDS. Pooling via per-block LDS bucket[1024].
// ---------------------------------------------------------------------------
__global__ __launch_bounds__(512, 4)
void gemm2(const unsigned short* __restrict__ H1, const unsigned short* __restrict__ Wimg,
           const float* __restrict__ b2, const float* __restrict__ W3,
           const float* __restrict__ b3, const int* __restrict__ batch,
           float* __restrict__ out) {
    __shared__ unsigned short Wlds[32768];   // 64 KB
    __shared__ float bucket[NMOL];           // 4 KB
    __shared__ float bL2[128], w3L[128];     // 1 KB
    __shared__ int uctr;

    const int tid = threadIdx.x;
    const int w = tid >> 6, lane = tid & 63;
    const int fl = lane & 15, qd = lane >> 4;
    const int ch = blockIdx.x >> 8;
    const int bslot = blockIdx.x & 255;

#pragma unroll
    for (int i = 0; i < 8; ++i) {
        int c = w * 8 + i;
        async16(&Wlds[c * 512],
                Wimg + ((c >> 5) << 15) + (ch << 14) + ((c & 31) << 9) + lane * 8);
    }
    bucket[tid] = 0.0f;
    bucket[tid + 512] = 0.0f;
    if (tid < 128) {
        bL2[tid] = b2[ch * 128 + tid];
        w3L[tid] = W3[ch * 128 + tid];
    }
    if (tid == 0) uctr = 0;
    __syncthreads();

    const float b3v = (ch == 0) ? b3[0] : 0.0f;   // add b3 once per atom

    int u;
    { int tt = 0; if (lane == 0) tt = atomicAdd(&uctr, 1);
      u = bslot + (__shfl(tt, 0) << 8); }
    const unsigned short* hp = H1 + (size_t)(u * 16 + fl) * 256 + qd * 8;
    short8 rr0 = *(const short8*)(hp);
    short8 rr1 = *(const short8*)(hp + 32);
    short8 rr2 = *(const short8*)(hp + 64);

    for (;;) {
        int un;
        { int tt = 0; if (lane == 0) tt = atomicAdd(&uctr, 1);
          un = bslot + (__shfl(tt, 0) << 8); }
        const bool more = (un < NU);
        const unsigned short* hpn =
            more ? (H1 + (size_t)(un * 16 + fl) * 256 + qd * 8) : hp;

        short8 rr[3] = {rr0, rr1, rr2};
        float4_t acc[8] = {};
#pragma unroll
        for (int s = 0; s < 8; ++s) {
            short8 hv = rr[s % 3];
            if (s < 5) rr[s % 3] = *(const short8*)(hp + (s + 3) * 32);
            else       rr[s % 3] = *(const short8*)(hpn + (s - 5) * 32);
            const int kc = s * 4 + qd;
#pragma unroll
            for (int nt = 0; nt < 8; ++nt) {
                short8 wf = wfrag_h(Wlds, nt * 16 + fl, kc);
                acc[nt] = __builtin_amdgcn_mfma_f32_16x16x32_bf16(hv, wf, acc[nt], 0, 0, 0);
            }
        }

        // acc[nt][r]: atom = u*16 + qd*4 + r, col = ch*128 + nt*16 + fl
        float rs[4] = {};
#pragma unroll
        for (int nt = 0; nt < 8; ++nt) {
            float bb = bL2[nt * 16 + fl];
            float w3 = w3L[nt * 16 + fl];
#pragma unroll
            for (int r = 0; r < 4; ++r)
                rs[r] += silu(acc[nt][r] + bb) * w3;
        }
#pragma unroll
        for (int r = 0; r < 4; ++r) {
            float v = rs[r];
            v += __shfl_xor(v, 1);
            v += __shfl_xor(v, 2);
            v += __shfl_xor(v, 4);
            v += __shfl_xor(v, 8);
            rs[r] = v;
        }
        if (fl == 0) {
            int atom0 = u * 16 + qd * 4;
            if (atom0 < N_ATOMS) {   // excludes pad atoms; %4==0 -> 4 rows valid
                int4 mb = *(const int4*)&batch[atom0];
                float v0 = rs[0] + b3v, v1 = rs[1] + b3v,
                      v2 = rs[2] + b3v, v3 = rs[3] + b3v;
                if (mb.x == mb.w) {
                    atomicAdd(&bucket[mb.x], (v0 + v1) + (v2 + v3));
                } else {
                    atomicAdd(&bucket[mb.x], v0);
                    atomicAdd(&bucket[mb.y], v1);
                    atomicAdd(&bucket[mb.z], v2);
                    atomicAdd(&bucket[mb.w], v3);
                }
            }
        }

        if (!more) break;
        rr0 = rr[2]; rr1 = rr[0]; rr2 = rr[1];
        u = un; hp = hpn;
    }
    __syncthreads();
#pragma unroll
    for (int i = 0; i < 2; ++i) {
        int m = tid + i * 512;
        float v = bucket[m];
        if (v != 0.0f) atomicAdd(&out[m], v * SCALE_C);
    }
}

// ---------------------------------------------------------------------------
extern "C" void kernel_launch(void* const* d_in, const int* in_sizes, int n_in,
                              void* d_out, int out_size, void* d_ws, size_t ws_size,
                              hipStream_t stream) {
    const float* A     = (const float*)d_in[0];
    const int*   batch = (const int*)d_in[1];
    const float* W1    = (const float*)d_in[2];
    const float* b1    = (const float*)d_in[3];
    const float* W2    = (const float*)d_in[4];
    const float* b2    = (const float*)d_in[5];
    const float* W3    = (const float*)d_in[6];
    const float* b3    = (const float*)d_in[7];
    float* out = (float*)d_out;

    unsigned short* H1  = (unsigned short*)d_ws;            // NPAD*256 bf16
    unsigned short* W1i = H1 + (size_t)NPAD * NFEAT;        // 65536 shorts
    unsigned short* W2i = W1i + 65536;                      // 65536 shorts
    unsigned short* Ab  = W2i + 65536;                      // NPAD*256 bf16

    prep<<<dim3(6768), 256, 0, stream>>>(W1, W2, A, W1i, W2i, Ab, out);
    gemm1<<<dim3(512), 512, 0, stream>>>(Ab, W1i, b1, H1);
    gemm2<<<dim3(512), 512, 0, stream>>>(H1, W2i, b2, W3, b3, batch, out);
}